// Round 12
// baseline (235.621 us; speedup 1.0000x reference)
//
#include <hip/hip_runtime.h>
#include <stdint.h>
#include <math.h>

#define S_LEN 2048
#define DIM   64
#define QBLK  64
#define KVBLK 32
#define NKV   (S_LEN / KVBLK)   // 64

typedef __attribute__((ext_vector_type(8))) short short8;
typedef __attribute__((ext_vector_type(4))) float f32x4;

// fp32 -> bf16 round-to-nearest-even (cold paths only)
static __device__ __forceinline__ unsigned short f2bf(float f) {
    union { float f; uint32_t u; } cv; cv.f = f;
    uint32_t u = cv.u;
    return (unsigned short)((u + 0x7fffu + ((u >> 16) & 1u)) >> 16);
}

static __device__ __forceinline__ float vmax3(float a, float b, float c) {
    float d;
    asm("v_max3_f32 %0, %1, %2, %3" : "=v"(d) : "v"(a), "v"(b), "v"(c));
    return d;
}

// ---------------- pre-kernel 1 (UNCHANGED): K fp32 -> bf16, chunk XOR swizzle ----------------
__global__ void cvt_k(const float* __restrict__ kp, unsigned short* __restrict__ kws) {
    const int idx = blockIdx.x * 256 + threadIdx.x;
    const int c   = idx & 7;
    const int s   = (idx >> 3) & (S_LEN - 1);
    const int bh  = idx >> 14;
    const float* src = kp + ((size_t)bh * S_LEN + s) * DIM + c * 8;
    const f32x4 a = *reinterpret_cast<const f32x4*>(src);
    const f32x4 b = *reinterpret_cast<const f32x4*>(src + 4);
    short8 t;
    t[0] = (short)f2bf(a[0]); t[1] = (short)f2bf(a[1]);
    t[2] = (short)f2bf(a[2]); t[3] = (short)f2bf(a[3]);
    t[4] = (short)f2bf(b[0]); t[5] = (short)f2bf(b[1]);
    t[6] = (short)f2bf(b[2]); t[7] = (short)f2bf(b[3]);
    unsigned short* dst = kws + ((size_t)bh * S_LEN + s) * DIM + (size_t)((c ^ (s & 7)) * 8);
    *reinterpret_cast<short8*>(dst) = t;
}

// ---------------- pre-kernel 2 (UNCHANGED): V^T [d][key], 32-key halves, kappa32 in-half ----
__global__ void cvt_v(const float* __restrict__ vp, unsigned short* __restrict__ vtws) {
    const int bh = blockIdx.x >> 5;
    const int T  = blockIdx.x & 31;
    const int tid = threadIdx.x;
    __shared__ unsigned short ldsT[DIM][72];   // [d][local key]

    const int i = tid >> 2;
    const int dbase = (tid & 3) * 16;
    const float* src = vp + ((size_t)bh * S_LEN + T * 64 + i) * DIM + dbase;
#pragma unroll
    for (int q4 = 0; q4 < 4; ++q4) {
        const f32x4 a = *reinterpret_cast<const f32x4*>(src + q4 * 4);
#pragma unroll
        for (int j = 0; j < 4; ++j) ldsT[dbase + q4 * 4 + j][i] = f2bf(a[j]);
    }
    __syncthreads();
#pragma unroll
    for (int hh = 0; hh < 2; ++hh) {
        const int slot = tid + hh * 256;          // 0..511 = (d, h, c_st)
        const int d = slot >> 3;
        const int h = (slot >> 2) & 1;
        const int c_st = slot & 3;
        const int cl = c_st ^ ((d >> 1) & 3);
        short8 t8;
#pragma unroll
        for (int j = 0; j < 8; ++j) {
            const int p = cl * 8 + j;
            const int kap = ((p & 4) << 2) | ((p & 16) >> 1) | ((p & 8) >> 1) | (p & 3);
            t8[j] = (short)ldsT[d][h * 32 + kap];
        }
        unsigned short* dst = vtws + ((size_t)bh * DIM + d) * S_LEN + T * 64 + h * 32 + c_st * 8;
        *reinterpret_cast<short8*>(dst) = t8;
    }
}

// ------------- main attention kernel: NO LDS, NO barriers; per-lane global frag loads -------------
// Fragment addresses proven byte-identical to R11's (stage->LDS->read) composition:
//   kf[nt][ks] <- kbase + (t*32 + nt*16 + r)*64 + (((ks<<2)|g)^(r&7))*8     (r&7 cancels cvt_k swizzle)
//   vf[nt]     <- vbase + (nt*16 + r)*2048 + t*32 + (g^((r>>1)&3))*8        (cancels cvt_v swizzle)
__global__ __launch_bounds__(256, 5)
void attn_fwd(const float* __restrict__ qp, const unsigned short* __restrict__ kws,
              const unsigned short* __restrict__ vtws, float* __restrict__ op) {
    const int lb = (blockIdx.x & 7) * 256 + (blockIdx.x >> 3);   // XCD swizzle (bijective, 2048 blocks)
    const int bh = lb >> 5;
    const int qb = lb & 31;
    const int tid  = threadIdx.x;
    const int wave = tid >> 6;
    const int lane = tid & 63;
    const int g = lane >> 4;
    const int r = lane & 15;

    const float*          qg    = qp   + (size_t)bh * (S_LEN * DIM);
    const unsigned short* kbase = kws  + (size_t)bh * (S_LEN * DIM);
    const unsigned short* vbase = vtws + (size_t)bh * (S_LEN * DIM);
    float*                og    = op   + (size_t)bh * (S_LEN * DIM);

    // Q frags (B-operand: col=q=lane&15, k=8g+i), pre-scaled by 0.125*log2(e) (base-2 scores)
    const float qscale = 0.125f * 1.44269504088896340736f;
    const int q0 = qb * QBLK + wave * 16;
    short8 qfrag[2];
    {
        const float* qrow = qg + (size_t)(q0 + r) * DIM;
#pragma unroll
        for (int ks = 0; ks < 2; ++ks) {
            const f32x4 a = *reinterpret_cast<const f32x4*>(qrow + ks * 32 + 8 * g);
            const f32x4 b = *reinterpret_cast<const f32x4*>(qrow + ks * 32 + 8 * g + 4);
            short8 t;
            t[0] = (short)f2bf(a[0] * qscale); t[1] = (short)f2bf(a[1] * qscale);
            t[2] = (short)f2bf(a[2] * qscale); t[3] = (short)f2bf(a[3] * qscale);
            t[4] = (short)f2bf(b[0] * qscale); t[5] = (short)f2bf(b[1] * qscale);
            t[6] = (short)f2bf(b[2] * qscale); t[7] = (short)f2bf(b[3] * qscale);
            qfrag[ks] = t;
        }
    }

    // O^T accumulators: o[ntd][rg] = O^T[d=ntd*16+4g+rg][q=r]; lane-uniform m,l
    f32x4 o[4];
#pragma unroll
    for (int nt = 0; nt < 4; ++nt) { f32x4 z = {0.f, 0.f, 0.f, 0.f}; o[nt] = z; }
    float m_run = -INFINITY, l_part = 0.0f;

    // hoisted per-lane fragment offsets (u16 units, 32-bit: per-bh arrays are 256KB)
    int koff[2][2], voff[4];
#pragma unroll
    for (int nt = 0; nt < 2; ++nt)
#pragma unroll
        for (int ks = 0; ks < 2; ++ks)
            koff[nt][ks] = (nt * 16 + r) * DIM + (((ks << 2) | g) ^ (r & 7)) * 8;
#pragma unroll
    for (int nt = 0; nt < 4; ++nt)
        voff[nt] = (nt * 16 + r) * S_LEN + (g ^ ((r >> 1) & 3)) * 8;

    const f32x4 z4 = {0.f, 0.f, 0.f, 0.f};

    for (int t = 0; t < NKV; ++t) {
        const int kt = t * (KVBLK * DIM);   // K window: +2048 u16 / tile
        const int vt = t * KVBLK;           // V window: +32 u16 / tile

        // ---- K fragments straight from L1/L2; S^T = K Q^T (base-2 domain) ----
        const short8 kf00 = *reinterpret_cast<const short8*>(kbase + kt + koff[0][0]);
        const short8 kf01 = *reinterpret_cast<const short8*>(kbase + kt + koff[0][1]);
        const short8 kf10 = *reinterpret_cast<const short8*>(kbase + kt + koff[1][0]);
        const short8 kf11 = *reinterpret_cast<const short8*>(kbase + kt + koff[1][1]);
        __builtin_amdgcn_s_setprio(1);
        f32x4 st0 = __builtin_amdgcn_mfma_f32_16x16x32_bf16(kf00, qfrag[0], z4, 0, 0, 0);
        f32x4 st1 = __builtin_amdgcn_mfma_f32_16x16x32_bf16(kf10, qfrag[0], z4, 0, 0, 0);
        st0 = __builtin_amdgcn_mfma_f32_16x16x32_bf16(kf01, qfrag[1], st0, 0, 0, 0);
        st1 = __builtin_amdgcn_mfma_f32_16x16x32_bf16(kf11, qfrag[1], st1, 0, 0, 0);
        __builtin_amdgcn_s_setprio(0);

        // ---- V fragments (issued before softmax so L2 latency hides under it) ----
        const short8 vf0 = *reinterpret_cast<const short8*>(vbase + vt + voff[0]);
        const short8 vf1 = *reinterpret_cast<const short8*>(vbase + vt + voff[1]);
        const short8 vf2 = *reinterpret_cast<const short8*>(vbase + vt + voff[2]);
        const short8 vf3 = *reinterpret_cast<const short8*>(vbase + vt + voff[3]);

        // ---- in-register online softmax (defer-max THR=8); 8 scores/lane ----
        const float a0 = vmax3(st0[0], st0[1], st0[2]);
        const float a1 = vmax3(st0[3], st1[0], st1[1]);
        const float a2 = fmaxf(st1[2], st1[3]);
        const float lane_mx = vmax3(a0, a1, a2);
        if (__any(lane_mx > m_run + 8.0f)) {
            float mx = fmaxf(lane_mx, __shfl_xor(lane_mx, 16));
            mx = fmaxf(mx, __shfl_xor(mx, 32));
            const float mnew = fmaxf(m_run, mx);
            const float al = __builtin_amdgcn_exp2f(m_run - mnew);   // -inf -> 0 on first tile
            m_run = mnew;
            l_part *= al;
#pragma unroll
            for (int nt = 0; nt < 4; ++nt) {
                f32x4 sc = o[nt];
                sc[0] *= al; sc[1] *= al; sc[2] *= al; sc[3] *= al;
                o[nt] = sc;
            }
        }
        f32x4 p0, p1;
        p0[0] = __builtin_amdgcn_exp2f(st0[0] - m_run);
        p0[1] = __builtin_amdgcn_exp2f(st0[1] - m_run);
        p0[2] = __builtin_amdgcn_exp2f(st0[2] - m_run);
        p0[3] = __builtin_amdgcn_exp2f(st0[3] - m_run);
        p1[0] = __builtin_amdgcn_exp2f(st1[0] - m_run);
        p1[1] = __builtin_amdgcn_exp2f(st1[1] - m_run);
        p1[2] = __builtin_amdgcn_exp2f(st1[2] - m_run);
        p1[3] = __builtin_amdgcn_exp2f(st1[3] - m_run);
        l_part += ((p0[0] + p0[1]) + (p0[2] + p0[3])) + ((p1[0] + p1[1]) + (p1[2] + p1[3]));

        // pfrag slot i = P[key = 16*(i>>2) + 4g + (i&3)] = kappa32(8g+i)
        short8 pfrag;
        {
            union { uint32_t u[4]; short8 v; } fr;
            asm("v_cvt_pk_bf16_f32 %0, %1, %2" : "=v"(fr.u[0]) : "v"(p0[0]), "v"(p0[1]));
            asm("v_cvt_pk_bf16_f32 %0, %1, %2" : "=v"(fr.u[1]) : "v"(p0[2]), "v"(p0[3]));
            asm("v_cvt_pk_bf16_f32 %0, %1, %2" : "=v"(fr.u[2]) : "v"(p1[0]), "v"(p1[1]));
            asm("v_cvt_pk_bf16_f32 %0, %1, %2" : "=v"(fr.u[3]) : "v"(p1[2]), "v"(p1[3]));
            pfrag = fr.v;
        }

        // ---- O^T += V^T P^T ----
        __builtin_amdgcn_s_setprio(1);
        o[0] = __builtin_amdgcn_mfma_f32_16x16x32_bf16(vf0, pfrag, o[0], 0, 0, 0);
        o[1] = __builtin_amdgcn_mfma_f32_16x16x32_bf16(vf1, pfrag, o[1], 0, 0, 0);
        o[2] = __builtin_amdgcn_mfma_f32_16x16x32_bf16(vf2, pfrag, o[2], 0, 0, 0);
        o[3] = __builtin_amdgcn_mfma_f32_16x16x32_bf16(vf3, pfrag, o[3], 0, 0, 0);
        __builtin_amdgcn_s_setprio(0);
    }

    // ---- epilogue: l reduce over lane-groups, O^T/l, float4 stores ----
    float lfull = l_part;
    lfull += __shfl_xor(lfull, 16);
    lfull += __shfl_xor(lfull, 32);
    const float inv = 1.0f / lfull;
    float* dst = og + (size_t)(q0 + r) * DIM + 4 * g;
#pragma unroll
    for (int nt = 0; nt < 4; ++nt) {
        f32x4 tt = o[nt];
        tt[0] *= inv; tt[1] *= inv; tt[2] *= inv; tt[3] *= inv;
        *reinterpret_cast<f32x4*>(dst + nt * 16) = tt;
    }
}

extern "C" void kernel_launch(void* const* d_in, const int* in_sizes, int n_in,
                              void* d_out, int out_size, void* d_ws, size_t ws_size,
                              hipStream_t stream) {
    const float* q = (const float*)d_in[0];
    const float* k = (const float*)d_in[1];
    const float* v = (const float*)d_in[2];
    float* out = (float*)d_out;
    unsigned short* kws  = (unsigned short*)d_ws;
    unsigned short* vtws = kws + (size_t)64 * S_LEN * DIM;
    cvt_k<<<dim3(64 * S_LEN * 8 / 256), 256, 0, stream>>>(k, kws);
    cvt_v<<<dim3(64 * (S_LEN / 64)), 256, 0, stream>>>(v, vtws);
    attn_fwd<<<dim3(2048), 256, 0, stream>>>(q, kws, vtws, out);
}

// Round 13
// 106.792 us; speedup vs baseline: 2.2064x; 2.2064x over previous
//
#include <hip/hip_runtime.h>
#include <stdint.h>
#include <math.h>

#define S_LEN 2048
#define DIM   64
#define QBLK  128
#define KVBLK 32
#define NKV   (S_LEN / KVBLK)   // 64

typedef __attribute__((ext_vector_type(8))) short short8;
typedef __attribute__((ext_vector_type(4))) float f32x4;

// fp32 -> bf16 round-to-nearest-even (cold paths only)
static __device__ __forceinline__ unsigned short f2bf(float f) {
    union { float f; uint32_t u; } cv; cv.f = f;
    uint32_t u = cv.u;
    return (unsigned short)((u + 0x7fffu + ((u >> 16) & 1u)) >> 16);
}

// async global->LDS, 16B per lane, LDS dest = wave-uniform base + lane*16
static __device__ __forceinline__ void gload16(const void* g, void* l) {
    __builtin_amdgcn_global_load_lds(
        (const __attribute__((address_space(1))) unsigned int*)g,
        (__attribute__((address_space(3))) unsigned int*)l, 16, 0, 0);
}

static __device__ __forceinline__ float vmax3(float a, float b, float c) {
    float d;
    asm("v_max3_f32 %0, %1, %2, %3" : "=v"(d) : "v"(a), "v"(b), "v"(c));
    return d;
}

// ---------------- pre-kernel 1 (UNCHANGED): K fp32 -> bf16, chunk XOR swizzle ----------------
__global__ void cvt_k(const float* __restrict__ kp, unsigned short* __restrict__ kws) {
    const int idx = blockIdx.x * 256 + threadIdx.x;
    const int c   = idx & 7;
    const int s   = (idx >> 3) & (S_LEN - 1);
    const int bh  = idx >> 14;
    const float* src = kp + ((size_t)bh * S_LEN + s) * DIM + c * 8;
    const f32x4 a = *reinterpret_cast<const f32x4*>(src);
    const f32x4 b = *reinterpret_cast<const f32x4*>(src + 4);
    short8 t;
    t[0] = (short)f2bf(a[0]); t[1] = (short)f2bf(a[1]);
    t[2] = (short)f2bf(a[2]); t[3] = (short)f2bf(a[3]);
    t[4] = (short)f2bf(b[0]); t[5] = (short)f2bf(b[1]);
    t[6] = (short)f2bf(b[2]); t[7] = (short)f2bf(b[3]);
    unsigned short* dst = kws + ((size_t)bh * S_LEN + s) * DIM + (size_t)((c ^ (s & 7)) * 8);
    *reinterpret_cast<short8*>(dst) = t;
}

// ---------------- pre-kernel 2 (UNCHANGED): V^T [d][key], 32-key halves, kappa32 in-half ----
__global__ void cvt_v(const float* __restrict__ vp, unsigned short* __restrict__ vtws) {
    const int bh = blockIdx.x >> 5;
    const int T  = blockIdx.x & 31;
    const int tid = threadIdx.x;
    __shared__ unsigned short ldsT[DIM][72];   // [d][local key]

    const int i = tid >> 2;
    const int dbase = (tid & 3) * 16;
    const float* src = vp + ((size_t)bh * S_LEN + T * 64 + i) * DIM + dbase;
#pragma unroll
    for (int q4 = 0; q4 < 4; ++q4) {
        const f32x4 a = *reinterpret_cast<const f32x4*>(src + q4 * 4);
#pragma unroll
        for (int j = 0; j < 4; ++j) ldsT[dbase + q4 * 4 + j][i] = f2bf(a[j]);
    }
    __syncthreads();
#pragma unroll
    for (int hh = 0; hh < 2; ++hh) {
        const int slot = tid + hh * 256;          // 0..511 = (d, h, c_st)
        const int d = slot >> 3;
        const int h = (slot >> 2) & 1;
        const int c_st = slot & 3;
        const int cl = c_st ^ ((d >> 1) & 3);
        short8 t8;
#pragma unroll
        for (int j = 0; j < 8; ++j) {
            const int p = cl * 8 + j;
            const int kap = ((p & 4) << 2) | ((p & 16) >> 1) | ((p & 8) >> 1) | (p & 3);
            t8[j] = (short)ldsT[d][h * 32 + kap];
        }
        unsigned short* dst = vtws + ((size_t)bh * DIM + d) * S_LEN + T * 64 + h * 32 + c_st * 8;
        *reinterpret_cast<short8*>(dst) = t8;
    }
}

// ---- pipeline phases as macros on directly-named locals (R8 technique: SROA-safe) ----
// QK(t): ST[mt][nt] = S^T tile, key = nt*16+4g+rg, q = r  (8 MFMA, reads klds)
#define QK_TILE(ST, KL)                                                                               \
    do {                                                                                              \
        __builtin_amdgcn_s_setprio(1);                                                                \
        _Pragma("unroll")                                                                             \
        for (int nt = 0; nt < 2; ++nt) {                                                              \
            const short8 kf0 = *reinterpret_cast<const short8*>((KL) + koff[nt][0]);                  \
            const short8 kf1 = *reinterpret_cast<const short8*>((KL) + koff[nt][1]);                  \
            ST[0][nt] = __builtin_amdgcn_mfma_f32_16x16x32_bf16(kf0, qfrag[0][0], z4, 0, 0, 0);       \
            ST[1][nt] = __builtin_amdgcn_mfma_f32_16x16x32_bf16(kf0, qfrag[1][0], z4, 0, 0, 0);       \
            ST[0][nt] = __builtin_amdgcn_mfma_f32_16x16x32_bf16(kf1, qfrag[0][1], ST[0][nt], 0, 0, 0);\
            ST[1][nt] = __builtin_amdgcn_mfma_f32_16x16x32_bf16(kf1, qfrag[1][1], ST[1][nt], 0, 0, 0);\
        }                                                                                             \
        __builtin_amdgcn_s_setprio(0);                                                                \
    } while (0)

// SM+PV on the PREVIOUS tile's scores (VALU chain + 8 MFMA, reads vlds)
#define SMPV(ST, VL)                                                                                  \
    do {                                                                                              \
        short8 pfA, pfB;                                                                              \
        _Pragma("unroll")                                                                             \
        for (int mt = 0; mt < 2; ++mt) {                                                              \
            const f32x4 s0 = ST[mt][0], s1 = ST[mt][1];                                               \
            const float a0 = vmax3(s0[0], s0[1], s0[2]);                                              \
            const float a1 = vmax3(s0[3], s1[0], s1[1]);                                              \
            const float lane_mx = vmax3(a0, a1, fmaxf(s1[2], s1[3]));                                 \
            if (__any(lane_mx > m_run[mt] + 8.0f)) {                                                  \
                float mx = fmaxf(lane_mx, __shfl_xor(lane_mx, 16));                                   \
                mx = fmaxf(mx, __shfl_xor(mx, 32));                                                   \
                const float mnew = fmaxf(m_run[mt], mx);                                              \
                const float al = __builtin_amdgcn_exp2f(m_run[mt] - mnew);                            \
                m_run[mt] = mnew;                                                                     \
                l_part[mt] *= al;                                                                     \
                _Pragma("unroll")                                                                     \
                for (int nt = 0; nt < 4; ++nt) {                                                      \
                    f32x4 sc = o[mt][nt];                                                             \
                    sc[0] *= al; sc[1] *= al; sc[2] *= al; sc[3] *= al;                               \
                    o[mt][nt] = sc;                                                                   \
                }                                                                                     \
            }                                                                                         \
            const float mnow = m_run[mt];                                                             \
            f32x4 p0, p1;                                                                             \
            p0[0] = __builtin_amdgcn_exp2f(ST[mt][0][0] - mnow);                                      \
            p0[1] = __builtin_amdgcn_exp2f(ST[mt][0][1] - mnow);                                      \
            p0[2] = __builtin_amdgcn_exp2f(ST[mt][0][2] - mnow);                                      \
            p0[3] = __builtin_amdgcn_exp2f(ST[mt][0][3] - mnow);                                      \
            p1[0] = __builtin_amdgcn_exp2f(ST[mt][1][0] - mnow);                                      \
            p1[1] = __builtin_amdgcn_exp2f(ST[mt][1][1] - mnow);                                      \
            p1[2] = __builtin_amdgcn_exp2f(ST[mt][1][2] - mnow);                                      \
            p1[3] = __builtin_amdgcn_exp2f(ST[mt][1][3] - mnow);                                      \
            l_part[mt] += ((p0[0] + p0[1]) + (p0[2] + p0[3])) + ((p1[0] + p1[1]) + (p1[2] + p1[3])); \
            union { uint32_t u[4]; short8 v; } fr;                                                    \
            asm("v_cvt_pk_bf16_f32 %0, %1, %2" : "=v"(fr.u[0]) : "v"(p0[0]), "v"(p0[1]));             \
            asm("v_cvt_pk_bf16_f32 %0, %1, %2" : "=v"(fr.u[1]) : "v"(p0[2]), "v"(p0[3]));             \
            asm("v_cvt_pk_bf16_f32 %0, %1, %2" : "=v"(fr.u[2]) : "v"(p1[0]), "v"(p1[1]));             \
            asm("v_cvt_pk_bf16_f32 %0, %1, %2" : "=v"(fr.u[3]) : "v"(p1[2]), "v"(p1[3]));             \
            if (mt == 0) pfA = fr.v; else pfB = fr.v;                                                 \
        }                                                                                             \
        __builtin_amdgcn_s_setprio(1);                                                                \
        _Pragma("unroll")                                                                             \
        for (int ntd = 0; ntd < 4; ++ntd) {                                                           \
            const short8 vf = *reinterpret_cast<const short8*>((VL) + voff[ntd]);                     \
            o[0][ntd] = __builtin_amdgcn_mfma_f32_16x16x32_bf16(vf, pfA, o[0][ntd], 0, 0, 0);         \
            o[1][ntd] = __builtin_amdgcn_mfma_f32_16x16x32_bf16(vf, pfB, o[1][ntd], 0, 0, 0);         \
        }                                                                                             \
        __builtin_amdgcn_s_setprio(0);                                                                \
    } while (0)

// -------- main attention: QBLK=128 (32 q/wave), KVBLK=32, T15 pipeline QK(t) || SMPV(t-1) --------
__global__ __launch_bounds__(256, 4)
void attn_fwd(const float* __restrict__ qp, const unsigned short* __restrict__ kws,
              const unsigned short* __restrict__ vtws, float* __restrict__ op) {
    const int lb = (blockIdx.x & 7) * 128 + (blockIdx.x >> 3);   // XCD swizzle (bijective, 1024)
    const int bh = lb >> 4;
    const int qb = lb & 15;
    const int tid  = threadIdx.x;
    const int wave = tid >> 6;
    const int lane = tid & 63;
    const int g = lane >> 4;
    const int r = lane & 15;

    __shared__ unsigned short klds[2][KVBLK * DIM];   // 2 x 4KB, linear (gload16)
    __shared__ unsigned short vlds[2][DIM * 32];      // 2 x 4KB, 64B rows (gload16)

    const float*          qg    = qp   + (size_t)bh * (S_LEN * DIM);
    const unsigned short* kbase = kws  + (size_t)bh * (S_LEN * DIM);
    const unsigned short* vbase = vtws + (size_t)bh * (S_LEN * DIM);
    float*                og    = op   + (size_t)bh * (S_LEN * DIM);

    // Q frags (B-operand: col=q, k=8g+i), pre-scaled by 0.125*log2(e) (base-2 scores)
    const float qscale = 0.125f * 1.44269504088896340736f;
    const int q0 = qb * QBLK + wave * 32;
    short8 qfrag[2][2];
#pragma unroll
    for (int mt = 0; mt < 2; ++mt) {
        const float* qrow = qg + (size_t)(q0 + mt * 16 + r) * DIM;
#pragma unroll
        for (int ks = 0; ks < 2; ++ks) {
            const f32x4 a = *reinterpret_cast<const f32x4*>(qrow + ks * 32 + 8 * g);
            const f32x4 b = *reinterpret_cast<const f32x4*>(qrow + ks * 32 + 8 * g + 4);
            short8 t;
            t[0] = (short)f2bf(a[0] * qscale); t[1] = (short)f2bf(a[1] * qscale);
            t[2] = (short)f2bf(a[2] * qscale); t[3] = (short)f2bf(a[3] * qscale);
            t[4] = (short)f2bf(b[0] * qscale); t[5] = (short)f2bf(b[1] * qscale);
            t[6] = (short)f2bf(b[2] * qscale); t[7] = (short)f2bf(b[3] * qscale);
            qfrag[mt][ks] = t;
        }
    }

    // O^T accumulators + lane-uniform m,l per mt
    f32x4 o[2][4];
    float m_run[2], l_part[2];
#pragma unroll
    for (int mt = 0; mt < 2; ++mt) {
#pragma unroll
        for (int nt = 0; nt < 4; ++nt) { f32x4 z = {0.f, 0.f, 0.f, 0.f}; o[mt][nt] = z; }
        m_run[mt] = -INFINITY; l_part[mt] = 0.0f;
    }

    // staging (R11-verified): K 1 gload16/wave; V 1 gload16/wave (kappa32 halves)
    const int srow = lane >> 3, schk = lane & 7;
    const int vd = wave * 16 + ((lane >> 2) & 15), vcst = lane & 3;
    auto stageK = [&](int t, int buf) {
        gload16(kbase + (size_t)(t * KVBLK + wave * 8 + srow) * DIM + schk * 8,
                &klds[buf][(wave * 8) * DIM]);
    };
    auto stageV = [&](int t, int buf) {
        gload16(vbase + (size_t)vd * S_LEN + (t >> 1) * 64 + (t & 1) * 32 + vcst * 8,
                &vlds[buf][wave * 512]);
    };

    // hoisted LDS read offsets (R11-verified)
    int koff[2][2], voff[4];
#pragma unroll
    for (int nt = 0; nt < 2; ++nt)
#pragma unroll
        for (int ks = 0; ks < 2; ++ks)
            koff[nt][ks] = (nt * 16 + r) * DIM + (((ks << 2) | g) ^ (r & 7)) * 8;
#pragma unroll
    for (int nt = 0; nt < 4; ++nt)
        voff[nt] = (nt * 16 + r) * 32 + (g ^ ((r >> 1) & 3)) * 8;

    const f32x4 z4 = {0.f, 0.f, 0.f, 0.f};
    const unsigned short* kl0 = &klds[0][0];
    const unsigned short* kl1 = &klds[1][0];
    const unsigned short* vl0 = &vlds[0][0];
    const unsigned short* vl1 = &vlds[1][0];

    // score double-state (even tiles -> stA, odd -> stB)
    f32x4 stA[2][2], stB[2][2];

    // ---- prologue ----
    stageK(0, 0);
    __syncthreads();
    // t = 0
    stageK(1, 1); stageV(0, 0);
    QK_TILE(stA, kl0);
    __syncthreads();
    // t = 1
    stageK(2, 0); stageV(1, 1);
    QK_TILE(stB, kl1);
    SMPV(stA, vl0);
    __syncthreads();

    // ---- main loop, 2-unrolled: QK(t) || SMPV(t-1) ----
    for (int tt = 2; tt < NKV; tt += 2) {
        // t = tt (even): K(t) in klds[0]; V(t-1) in vlds[1]
        stageK(tt + 1, 1);
        stageV(tt, 0);
        QK_TILE(stA, kl0);
        SMPV(stB, vl1);
        __syncthreads();
        // t = tt+1 (odd): K(t) in klds[1]; V(t-1) in vlds[0]
        if (tt + 2 < NKV) stageK(tt + 2, 0);
        stageV(tt + 1, 1);
        QK_TILE(stB, kl1);
        SMPV(stA, vl0);
        __syncthreads();
    }
    // ---- epilogue: last tile (NKV-1, odd) ----
    SMPV(stB, vl1);

#pragma unroll
    for (int mt = 0; mt < 2; ++mt) {
        float lfull = l_part[mt];
        lfull += __shfl_xor(lfull, 16);
        lfull += __shfl_xor(lfull, 32);
        const float inv = 1.0f / lfull;
        float* dst = og + (size_t)(q0 + mt * 16 + r) * DIM + 4 * g;
#pragma unroll
        for (int ntd = 0; ntd < 4; ++ntd) {
            f32x4 tt = o[mt][ntd];
            tt[0] *= inv; tt[1] *= inv; tt[2] *= inv; tt[3] *= inv;
            *reinterpret_cast<f32x4*>(dst + ntd * 16) = tt;
        }
    }
}

extern "C" void kernel_launch(void* const* d_in, const int* in_sizes, int n_in,
                              void* d_out, int out_size, void* d_ws, size_t ws_size,
                              hipStream_t stream) {
    const float* q = (const float*)d_in[0];
    const float* k = (const float*)d_in[1];
    const float* v = (const float*)d_in[2];
    float* out = (float*)d_out;
    unsigned short* kws  = (unsigned short*)d_ws;
    unsigned short* vtws = kws + (size_t)64 * S_LEN * DIM;
    cvt_k<<<dim3(64 * S_LEN * 8 / 256), 256, 0, stream>>>(k, kws);
    cvt_v<<<dim3(64 * (S_LEN / 64)), 256, 0, stream>>>(v, vtws);
    attn_fwd<<<dim3(1024), 256, 0, stream>>>(q, kws, vtws, out);
}